// Round 14
// baseline (311.767 us; speedup 1.0000x reference)
//
#include <hip/hip_runtime.h>
#include <hip/hip_fp16.h>

#define N_NODES 65536
#define N_EDGES 1048576
#define NBUCK 256                 // coarse buckets (dst>>8), 256 nodes each
#define PBLOCKS 256               // partition blocks
#define EPB (N_EDGES / PBLOCKS)   // 4096 edges per partition block
#define K4CAP 6144                // finalize LDS staging capacity (mean 4096, sigma 64)
constexpr float NEG = 0.2f;
constexpr float EPS_ = 1e-16f;
constexpr float WSHIFT = 2.7725887f;   // ln(16): softmax-invariant shift, fp16 overflow guard

typedef __attribute__((ext_vector_type(8))) short bf16x8;
typedef __attribute__((ext_vector_type(4))) float f32x4;

__device__ __forceinline__ unsigned short f2bf(float f) {
    unsigned int u = __float_as_uint(f);
    return (unsigned short)((u + 0x7fffu + ((u >> 16) & 1u)) >> 16);
}
__device__ __forceinline__ unsigned short f2h(float f) {
    __half_raw r = __half_raw(__float2half(f));
    return r.x;
}
__device__ __forceinline__ __half2 u2h2(unsigned int u) {
    union { unsigned int u; __half2 h; } c; c.u = u; return c.h;
}
__device__ __forceinline__ unsigned int h22u(__half2 h) {
    union { unsigned int u; __half2 h; } c; c.h = h; return c.u;
}
__device__ __forceinline__ float lrelu_exp_s(float l) {
    return __expf(fmaxf(l, NEG * l) - WSHIFT);
}

// ---------------- CSR build: radix partition by dst>>8, no global atomics ----------------

__global__ __launch_bounds__(256) void coarse_hist(const int* __restrict__ ei,
                                                   int* __restrict__ hist_mat) {
    __shared__ int h[NBUCK];
    int t = threadIdx.x;
    h[t] = 0;
    __syncthreads();
    int base = blockIdx.x * EPB;
    #pragma unroll
    for (int i = 0; i < EPB / 256; ++i) {
        int d = ei[N_EDGES + base + i * 256 + t];
        atomicAdd(&h[d >> 8], 1);
    }
    __syncthreads();
    hist_mat[t * PBLOCKS + blockIdx.x] = h[t];
}

__global__ __launch_bounds__(1024) void scan_a(const int* __restrict__ in,
                                               int* __restrict__ out,
                                               int* __restrict__ bsum) {
    __shared__ int sm[1024];
    int t = threadIdx.x, i = blockIdx.x * 1024 + t;
    int v = in[i];
    sm[t] = v;
    __syncthreads();
    for (int off = 1; off < 1024; off <<= 1) {
        int u = (t >= off) ? sm[t - off] : 0;
        __syncthreads();
        sm[t] += u;
        __syncthreads();
    }
    out[i] = sm[t] - v;
    if (t == 1023) bsum[blockIdx.x] = sm[t];
}

__global__ __launch_bounds__(1024) void scan_c(int* __restrict__ arr,
                                               const int* __restrict__ bsum) {
    __shared__ int off[64];
    int t = threadIdx.x;
    if (t < 64) {
        int v = bsum[t];
        int incl = v;
        #pragma unroll
        for (int o = 1; o < 64; o <<= 1) {
            int u = __shfl_up(incl, o);
            if (t >= o) incl += u;
        }
        off[t] = incl - v;
    }
    __syncthreads();
    int i = blockIdx.x * 1024 + t;
    arr[i] += off[blockIdx.x];
}

__global__ __launch_bounds__(256) void partition_kernel(const int* __restrict__ ei,
                                                        const int* __restrict__ cursor_mat,
                                                        unsigned int* __restrict__ edge_part) {
    __shared__ int h[NBUCK];
    __shared__ int start[NBUCK];
    __shared__ int cur[NBUCK];
    __shared__ int gcur[NBUCK];
    __shared__ unsigned int stage[EPB];
    int t = threadIdx.x;
    h[t] = 0;
    gcur[t] = cursor_mat[t * PBLOCKS + blockIdx.x];
    __syncthreads();
    unsigned int ent[EPB / 256];
    int base = blockIdx.x * EPB;
    #pragma unroll
    for (int i = 0; i < EPB / 256; ++i) {
        int e = base + i * 256 + t;
        int s = ei[e], d = ei[N_EDGES + e];
        ent[i] = ((unsigned int)s << 16) | (unsigned int)d;   // src,dst both < 2^16
        atomicAdd(&h[d >> 8], 1);
    }
    __syncthreads();
    int v = h[t];
    start[t] = v;
    __syncthreads();
    for (int off = 1; off < 256; off <<= 1) {
        int u = (t >= off) ? start[t - off] : 0;
        __syncthreads();
        start[t] += u;
        __syncthreads();
    }
    int excl = start[t] - v;
    start[t] = excl;
    cur[t] = excl;
    __syncthreads();
    #pragma unroll
    for (int i = 0; i < EPB / 256; ++i) {
        int b = (int)((ent[i] & 0xffffu) >> 8);
        int slot = atomicAdd(&cur[b], 1);
        stage[slot] = ent[i];
    }
    __syncthreads();
    int s0 = t * (EPB / 256);
    #pragma unroll
    for (int i = 0; i < EPB / 256; ++i) {
        unsigned int p = stage[s0 + i];
        int b = (int)((p & 0xffffu) >> 8);
        edge_part[gcur[b] + (s0 + i - start[b])] = p;
    }
}

__global__ __launch_bounds__(256) void finalize_kernel(const unsigned int* __restrict__ edge_part,
                                                       const int* __restrict__ cursor_mat,
                                                       int* __restrict__ row_ptr,
                                                       int* __restrict__ csr_src) {
    __shared__ int h[256];
    __shared__ int sc[256];
    __shared__ int cur[256];
    __shared__ unsigned short stage[K4CAP];
    int t = threadIdx.x;
    int b = blockIdx.x;
    if (b == NBUCK - 1 && t == 0) row_ptr[N_NODES] = N_EDGES;
    int cs = cursor_mat[b * PBLOCKS];
    int ce = (b == NBUCK - 1) ? N_EDGES : cursor_mat[(b + 1) * PBLOCKS];
    int cnt = ce - cs;
    h[t] = 0;
    __syncthreads();
    for (int i = t; i < cnt; i += 256)
        atomicAdd(&h[edge_part[cs + i] & 0xffu], 1);
    __syncthreads();
    int v = h[t];
    sc[t] = v;
    __syncthreads();
    for (int off = 1; off < 256; off <<= 1) {
        int u = (t >= off) ? sc[t - off] : 0;
        __syncthreads();
        sc[t] += u;
        __syncthreads();
    }
    int excl = sc[t] - v;
    row_ptr[b * 256 + t] = cs + excl;
    cur[t] = excl;
    __syncthreads();
    if (cnt <= K4CAP) {
        for (int i = t; i < cnt; i += 256) {
            unsigned int p = edge_part[cs + i];
            int slot = atomicAdd(&cur[p & 0xffu], 1);
            stage[slot] = (unsigned short)(p >> 16);
        }
        __syncthreads();
        for (int i = t; i < cnt; i += 256)
            csr_src[cs + i] = (int)stage[i];
    } else {
        for (int i = t; i < cnt; i += 256) {
            unsigned int p = edge_part[cs + i];
            int slot = atomicAdd(&cur[p & 0xffu], 1);
            csr_src[cs + slot] = (int)(p >> 16);
        }
    }
}

// ---------------- GEMM via MFMA 16x16x32 bf16 ----------------
// layer 1: fp32 X in; h1 out fp16 HEAD-MAJOR: h1hm[head][node][32]

__global__ __launch_bounds__(256) void gemm1_mfma(const float* __restrict__ X,
                                                  const float* __restrict__ W,
                                                  unsigned short* __restrict__ H) {
    constexpr int OUTC = 128;
    constexpr int NT = OUTC / 16;
    extern __shared__ unsigned short Wl[];
    int t = threadIdx.x;
    for (int idx = t; idx < OUTC * 128; idx += 256) {
        int j = idx & 7;
        int ln = (idx >> 3) & 63;
        int fc = idx >> 9;
        int kc = fc & 3, ct = fc >> 2;
        int k = kc * 32 + (ln >> 4) * 8 + j;
        int n = ct * 16 + (ln & 15);
        Wl[idx] = (unsigned short)f2bf(W[k * OUTC + n]);
    }
    __syncthreads();
    int wave = t >> 6, lane = t & 63;
    int m = lane & 15, quad = lane >> 4;
    int node_base = blockIdx.x * 64 + wave * 16;
    const float* xrow = X + (size_t)(node_base + m) * 128 + quad * 8;
    bf16x8 a[4];
    #pragma unroll
    for (int kc = 0; kc < 4; ++kc) {
        float4 u = *(const float4*)(xrow + kc * 32);
        float4 v = *(const float4*)(xrow + kc * 32 + 4);
        bf16x8 af;
        af[0] = (short)f2bf(u.x); af[1] = (short)f2bf(u.y);
        af[2] = (short)f2bf(u.z); af[3] = (short)f2bf(u.w);
        af[4] = (short)f2bf(v.x); af[5] = (short)f2bf(v.y);
        af[6] = (short)f2bf(v.z); af[7] = (short)f2bf(v.w);
        a[kc] = af;
    }
    #pragma unroll
    for (int ct = 0; ct < NT; ++ct) {
        f32x4 acc = {0.f, 0.f, 0.f, 0.f};
        #pragma unroll
        for (int kc = 0; kc < 4; ++kc) {
            bf16x8 bfr = *(const bf16x8*)(Wl + ((ct * 4 + kc) * 64 + lane) * 8);
            acc = __builtin_amdgcn_mfma_f32_16x16x32_bf16(a[kc], bfr, acc, 0, 0, 0);
        }
        int ch = ct * 16 + m;
        int hd = ch >> 5, c32 = ch & 31;
        #pragma unroll
        for (int r = 0; r < 4; ++r) {
            int row = quad * 4 + r;
            H[((size_t)hd * N_NODES + node_base + row) * 32 + c32] = f2h(acc[r]);
        }
    }
}

// layer 2: bf16 X in HEAD-MAJOR x2hm[kc][node][32]; h2 out fp16 CH-SPLIT h2cs[c>>5][node][32]

__global__ __launch_bounds__(256) void gemm2_mfma(const unsigned short* __restrict__ X,
                                                  const float* __restrict__ W,
                                                  unsigned short* __restrict__ H) {
    constexpr int OUTC = 64;
    constexpr int NT = OUTC / 16;
    extern __shared__ unsigned short Wl[];
    int t = threadIdx.x;
    for (int idx = t; idx < OUTC * 128; idx += 256) {
        int j = idx & 7;
        int ln = (idx >> 3) & 63;
        int fc = idx >> 9;
        int kc = fc & 3, ct = fc >> 2;
        int k = kc * 32 + (ln >> 4) * 8 + j;
        int n = ct * 16 + (ln & 15);
        Wl[idx] = (unsigned short)f2bf(W[k * OUTC + n]);
    }
    __syncthreads();
    int wave = t >> 6, lane = t & 63;
    int m = lane & 15, quad = lane >> 4;
    int node_base = blockIdx.x * 64 + wave * 16;
    bf16x8 a[4];
    #pragma unroll
    for (int kc = 0; kc < 4; ++kc)
        a[kc] = *(const bf16x8*)(X + ((size_t)kc * N_NODES + node_base + m) * 32 + quad * 8);
    #pragma unroll
    for (int ct = 0; ct < NT; ++ct) {
        f32x4 acc = {0.f, 0.f, 0.f, 0.f};
        #pragma unroll
        for (int kc = 0; kc < 4; ++kc) {
            bf16x8 bfr = *(const bf16x8*)(Wl + ((ct * 4 + kc) * 64 + lane) * 8);
            acc = __builtin_amdgcn_mfma_f32_16x16x32_bf16(a[kc], bfr, acc, 0, 0, 0);
        }
        int ch = ct * 16 + m;
        int cs = ch >> 5, c32 = ch & 31;
        #pragma unroll
        for (int r = 0; r < 4; ++r) {
            int row = quad * 4 + r;
            H[((size_t)cs * N_NODES + node_base + row) * 32 + c32] = f2h(acc[r]);
        }
    }
}

// ---------------- attention logits (head-major / ch-split fp16 h) ----------------

__global__ __launch_bounds__(256) void att1_kernel(const unsigned int* __restrict__ h1u,
                                                   const float* __restrict__ as_w,
                                                   const float* __restrict__ ad_w,
                                                   float* __restrict__ a_src,
                                                   float* __restrict__ a_dst) {
    int node = (blockIdx.x * 256 + threadIdx.x) >> 6;
    int lane = threadIdx.x & 63;
    // channel pair (lane*2, lane*2+1): head = lane>>4, uint idx within row = lane&15
    __half2 p = u2h2(h1u[((size_t)(lane >> 4) * N_NODES + node) * 16 + (lane & 15)]);
    float h0 = __low2float(p), h1v = __high2float(p);
    float2 sw = *(const float2*)(as_w + lane * 2);
    float2 dw = *(const float2*)(ad_w + lane * 2);
    float ps = h0 * sw.x + h1v * sw.y;
    float pd = h0 * dw.x + h1v * dw.y;
    #pragma unroll
    for (int m = 1; m < 16; m <<= 1) {
        ps += __shfl_xor(ps, m);
        pd += __shfl_xor(pd, m);
    }
    if ((lane & 15) == 0) {
        a_src[node * 4 + (lane >> 4)] = ps;
        a_dst[node * 4 + (lane >> 4)] = pd;
    }
}

__global__ __launch_bounds__(256) void att2_kernel(const __half* __restrict__ h2h,
                                                   const float* __restrict__ as_w,
                                                   const float* __restrict__ ad_w,
                                                   float* __restrict__ a_src,
                                                   float* __restrict__ a_dst) {
    int node = (blockIdx.x * 256 + threadIdx.x) >> 6;
    int lane = threadIdx.x & 63;
    float v = __half2float(h2h[((size_t)(lane >> 5) * N_NODES + node) * 32 + (lane & 31)]);
    float ps = v * as_w[lane];
    float pd = v * ad_w[lane];
    #pragma unroll
    for (int m = 1; m < 64; m <<= 1) {
        ps += __shfl_xor(ps, m);
        pd += __shfl_xor(pd, m);
    }
    if (lane == 0) {
        a_src[node] = ps;
        a_dst[node] = pd;
    }
}

// ---------------- edge aggregation: HEAD-SLICED, L2-resident 4MB gather tables --------
// agg1: block handles ONE head (head = blockIdx&3 -> fixed head per XCD under
// round-robin dispatch). Half-wave (32 ln) per node: 8 row-slots x 4 lanes x uint4
// (row = 32 f16 = 64B). Batch = 8 edges, w by lanes j8=ln&7 (4 redundant groups;
// denom reduced within group). One shfl per lane per batch.

__global__ __launch_bounds__(256) void agg1_kernel(const int* __restrict__ row_ptr,
                                                   const int* __restrict__ csr_src,
                                                   const unsigned short* __restrict__ h1hm,
                                                   const float* __restrict__ a_src,
                                                   const float* __restrict__ a_dst,
                                                   const float* __restrict__ b1,
                                                   unsigned short* __restrict__ x2hm) {
    int head = blockIdx.x & 3;
    int nb = blockIdx.x >> 2;
    int t = threadIdx.x;
    int lane = t & 63;
    int half = lane >> 5;
    int ln = lane & 31;
    int n = nb * 8 + (t >> 6) * 2 + half;
    int j8 = ln & 7;
    int slot = ln >> 2;            // 8 row-slots
    int li = ln & 3;               // 16B segment within row
    const unsigned short* tbl = h1hm + (size_t)head * N_NODES * 32;
    float adw = a_dst[n * 4 + head];
    int e = row_ptr[n], end = row_ptr[n + 1];
    __half2 acc0 = u2h2(0u), acc1 = u2h2(0u), acc2 = u2h2(0u), acc3 = u2h2(0u);
    float denom = 0.f;
    while (e < end) {
        int mb = end - e;
        if (mb > 8) mb = 8;
        int s_l = csr_src[e + (j8 < mb ? j8 : 0)];
        float l = a_src[s_l * 4 + head] + adw;
        float wv = (j8 < mb) ? lrelu_exp_s(l) : 0.f;
        denom += wv;
        unsigned int pack = ((unsigned int)f2h(wv) << 16) | (unsigned int)s_l;
        unsigned int pk = __shfl(pack, half * 32 + slot);
        unsigned int wu = pk >> 16;
        __half2 w2 = u2h2(wu | (wu << 16));
        unsigned int s = pk & 0xffffu;
        uint4 hv = *(const uint4*)(tbl + (size_t)s * 32 + li * 8);
        acc0 = __hfma2(w2, u2h2(hv.x), acc0);
        acc1 = __hfma2(w2, u2h2(hv.y), acc1);
        acc2 = __hfma2(w2, u2h2(hv.z), acc2);
        acc3 = __hfma2(w2, u2h2(hv.w), acc3);
        e += 8;
    }
    // acc: sum the 8 row-slots (xor 4,8,16 stay within half)
    #pragma unroll
    for (int m = 4; m < 32; m <<= 1) {
        acc0 = __hadd2(acc0, u2h2(__shfl_xor(h22u(acc0), m)));
        acc1 = __hadd2(acc1, u2h2(__shfl_xor(h22u(acc1), m)));
        acc2 = __hadd2(acc2, u2h2(__shfl_xor(h22u(acc2), m)));
        acc3 = __hadd2(acc3, u2h2(__shfl_xor(h22u(acc3), m)));
    }
    // denom: each 8-lane group holds all 8 j8 values -> xor 1,2,4 gives batch totals
    #pragma unroll
    for (int m = 1; m < 8; m <<= 1) denom += __shfl_xor(denom, m);
    if (slot == 0) {               // lanes li = 0..3 per half
        float inv = 1.f / (denom + EPS_);
        int c0 = li * 8;           // within-head channel base
        float v[8];
        v[0] = __low2float(acc0); v[1] = __high2float(acc0);
        v[2] = __low2float(acc1); v[3] = __high2float(acc1);
        v[4] = __low2float(acc2); v[5] = __high2float(acc2);
        v[6] = __low2float(acc3); v[7] = __high2float(acc3);
        unsigned int o[4];
        #pragma unroll
        for (int i = 0; i < 4; ++i) {
            float u0 = v[2 * i] * inv + b1[head * 32 + c0 + 2 * i];
            float u1 = v[2 * i + 1] * inv + b1[head * 32 + c0 + 2 * i + 1];
            u0 = 1.f / (1.f + __expf(-u0));
            u1 = 1.f / (1.f + __expf(-u1));
            o[i] = (unsigned int)f2bf(u0) | ((unsigned int)f2bf(u1) << 16);
        }
        *(uint4*)(x2hm + ((size_t)head * N_NODES + n) * 32 + c0) =
            make_uint4(o[0], o[1], o[2], o[3]);
    }
}

// agg2: block handles ONE channel-half (cs = blockIdx&1); denom recomputed per slice.

__global__ __launch_bounds__(256) void agg2_kernel(const int* __restrict__ row_ptr,
                                                   const int* __restrict__ csr_src,
                                                   const unsigned short* __restrict__ h2cs,
                                                   const float* __restrict__ a_src,
                                                   const float* __restrict__ a_dst,
                                                   const float* __restrict__ b2,
                                                   float* __restrict__ out) {
    int cs = blockIdx.x & 1;
    int nb = blockIdx.x >> 1;
    int t = threadIdx.x;
    int lane = t & 63;
    int half = lane >> 5;
    int ln = lane & 31;
    int n = nb * 8 + (t >> 6) * 2 + half;
    int j8 = ln & 7;
    int slot = ln >> 2;
    int li = ln & 3;
    const unsigned short* tbl = h2cs + (size_t)cs * N_NODES * 32;
    float ad = a_dst[n];
    int e = row_ptr[n], end = row_ptr[n + 1];
    __half2 acc0 = u2h2(0u), acc1 = u2h2(0u), acc2 = u2h2(0u), acc3 = u2h2(0u);
    float denom = 0.f;
    while (e < end) {
        int mb = end - e;
        if (mb > 8) mb = 8;
        int s_l = csr_src[e + (j8 < mb ? j8 : 0)];
        float l = a_src[s_l] + ad;
        float wv = (j8 < mb) ? lrelu_exp_s(l) : 0.f;
        denom += wv;
        unsigned int pack = ((unsigned int)f2h(wv) << 16) | (unsigned int)s_l;
        unsigned int pk = __shfl(pack, half * 32 + slot);
        unsigned int wu = pk >> 16;
        __half2 w2 = u2h2(wu | (wu << 16));
        unsigned int s = pk & 0xffffu;
        uint4 hv = *(const uint4*)(tbl + (size_t)s * 32 + li * 8);
        acc0 = __hfma2(w2, u2h2(hv.x), acc0);
        acc1 = __hfma2(w2, u2h2(hv.y), acc1);
        acc2 = __hfma2(w2, u2h2(hv.z), acc2);
        acc3 = __hfma2(w2, u2h2(hv.w), acc3);
        e += 8;
    }
    #pragma unroll
    for (int m = 4; m < 32; m <<= 1) {
        acc0 = __hadd2(acc0, u2h2(__shfl_xor(h22u(acc0), m)));
        acc1 = __hadd2(acc1, u2h2(__shfl_xor(h22u(acc1), m)));
        acc2 = __hadd2(acc2, u2h2(__shfl_xor(h22u(acc2), m)));
        acc3 = __hadd2(acc3, u2h2(__shfl_xor(h22u(acc3), m)));
    }
    #pragma unroll
    for (int m = 1; m < 8; m <<= 1) denom += __shfl_xor(denom, m);
    if (slot == 0) {
        float inv = 1.f / (denom + EPS_);
        int c0 = cs * 32 + li * 8;
        float v[8];
        v[0] = __low2float(acc0); v[1] = __high2float(acc0);
        v[2] = __low2float(acc1); v[3] = __high2float(acc1);
        v[4] = __low2float(acc2); v[5] = __high2float(acc2);
        v[6] = __low2float(acc3); v[7] = __high2float(acc3);
        float o[8];
        #pragma unroll
        for (int i = 0; i < 8; ++i) {
            float u = v[i] * inv + b2[c0 + i];
            o[i] = 1.f / (1.f + __expf(-u));
        }
        float4* dst = (float4*)(out + (size_t)n * 64 + c0);
        dst[0] = make_float4(o[0], o[1], o[2], o[3]);
        dst[1] = make_float4(o[4], o[5], o[6], o[7]);
    }
}

// ---------------- launch ----------------

extern "C" void kernel_launch(void* const* d_in, const int* in_sizes, int n_in,
                              void* d_out, int out_size, void* d_ws, size_t ws_size,
                              hipStream_t stream) {
    (void)in_sizes; (void)n_in; (void)out_size; (void)ws_size;
    const float* x   = (const float*)d_in[0];
    const int*   ei  = (const int*)d_in[1];
    const float* W1  = (const float*)d_in[2];
    const float* as1 = (const float*)d_in[3];
    const float* ad1 = (const float*)d_in[4];
    const float* b1  = (const float*)d_in[5];
    const float* W2  = (const float*)d_in[6];
    const float* as2 = (const float*)d_in[7];
    const float* ad2 = (const float*)d_in[8];
    const float* b2  = (const float*)d_in[9];
    float* out = (float*)d_out;

    char* p = (char*)d_ws;
    auto alloc = [&](size_t bytes) -> void* {
        void* r = (void*)p;
        p += (bytes + 255) & ~(size_t)255;
        return r;
    };
    int* hist_mat   = (int*)alloc((size_t)NBUCK * PBLOCKS * 4);
    int* cursor_mat = (int*)alloc((size_t)NBUCK * PBLOCKS * 4);
    int* bsum       = (int*)alloc(64 * 4);
    unsigned int* edge_part = (unsigned int*)alloc((size_t)N_EDGES * 4);
    int* row_ptr    = (int*)alloc((size_t)(N_NODES + 1) * 4);
    int* csr_src    = (int*)alloc((size_t)N_EDGES * 4);
    unsigned short* h1 = (unsigned short*)alloc((size_t)N_NODES * 128 * 2);  // fp16 head-major
    float* a_src1   = (float*)alloc((size_t)N_NODES * 4 * 4);
    float* a_dst1   = (float*)alloc((size_t)N_NODES * 4 * 4);
    unsigned short* x2 = (unsigned short*)alloc((size_t)N_NODES * 128 * 2);  // bf16 head-major
    unsigned short* h2 = (unsigned short*)alloc((size_t)N_NODES * 64 * 2);   // fp16 ch-split
    float* a_src2   = (float*)alloc((size_t)N_NODES * 4);
    float* a_dst2   = (float*)alloc((size_t)N_NODES * 4);

    // CSR build (atomic-free radix partition)
    coarse_hist<<<PBLOCKS, 256, 0, stream>>>(ei, hist_mat);
    scan_a<<<64, 1024, 0, stream>>>(hist_mat, cursor_mat, bsum);
    scan_c<<<64, 1024, 0, stream>>>(cursor_mat, bsum);
    partition_kernel<<<PBLOCKS, 256, 0, stream>>>(ei, cursor_mat, edge_part);
    finalize_kernel<<<NBUCK, 256, 0, stream>>>(edge_part, cursor_mat, row_ptr, csr_src);

    // layer 1
    gemm1_mfma<<<N_NODES / 64, 256, 128 * 128 * 2, stream>>>(x, W1, h1);
    att1_kernel<<<N_NODES / 4, 256, 0, stream>>>((const unsigned int*)h1, as1, ad1, a_src1, a_dst1);
    agg1_kernel<<<(N_NODES / 8) * 4, 256, 0, stream>>>(row_ptr, csr_src, h1,
                                                       a_src1, a_dst1, b1, x2);

    // layer 2
    gemm2_mfma<<<N_NODES / 64, 256, 128 * 64 * 2, stream>>>(x2, W2, h2);
    att2_kernel<<<N_NODES / 4, 256, 0, stream>>>((const __half*)h2, as2, ad2, a_src2, a_dst2);
    agg2_kernel<<<(N_NODES / 8) * 2, 256, 0, stream>>>(row_ptr, csr_src, h2,
                                                       a_src2, a_dst2, b2, out);
}

// Round 15
// 244.837 us; speedup vs baseline: 1.2734x; 1.2734x over previous
//
#include <hip/hip_runtime.h>
#include <hip/hip_fp16.h>

#define N_NODES 65536
#define N_EDGES 1048576
#define NBUCK 256                 // coarse buckets (dst>>8), 256 nodes each
#define PBLOCKS 1024              // partition blocks (4 blocks/CU)
#define EPB (N_EDGES / PBLOCKS)   // 1024 edges per partition block
#define K4CAP 6144                // finalize LDS staging capacity (mean 4096, sigma 64)
constexpr float NEG = 0.2f;
constexpr float EPS_ = 1e-16f;
constexpr float WSHIFT = 2.7725887f;   // ln(16): softmax-invariant shift, fp16 overflow guard

typedef __attribute__((ext_vector_type(8))) short bf16x8;
typedef __attribute__((ext_vector_type(4))) float f32x4;

__device__ __forceinline__ unsigned short f2bf(float f) {
    unsigned int u = __float_as_uint(f);
    return (unsigned short)((u + 0x7fffu + ((u >> 16) & 1u)) >> 16);
}
__device__ __forceinline__ unsigned short f2h(float f) {
    __half_raw r = __half_raw(__float2half(f));
    return r.x;
}
__device__ __forceinline__ __half2 u2h2(unsigned int u) {
    union { unsigned int u; __half2 h; } c; c.u = u; return c.h;
}
__device__ __forceinline__ unsigned int h22u(__half2 h) {
    union { unsigned int u; __half2 h; } c; c.h = h; return c.u;
}
__device__ __forceinline__ float lrelu_exp_s(float l) {
    return __expf(fmaxf(l, NEG * l) - WSHIFT);
}

// ---------------- CSR build: radix partition by dst>>8, no global atomics ----------------
// hist_mat/cursor_mat: [bucket][pblock] (bucket-major), NBUCK x PBLOCKS

__global__ __launch_bounds__(256) void coarse_hist(const int* __restrict__ ei,
                                                   int* __restrict__ hist_mat) {
    __shared__ int h[NBUCK];
    int t = threadIdx.x;
    h[t] = 0;
    __syncthreads();
    int base = blockIdx.x * EPB;
    #pragma unroll
    for (int i = 0; i < EPB / 256; ++i) {
        int d = ei[N_EDGES + base + i * 256 + t];
        atomicAdd(&h[d >> 8], 1);
    }
    __syncthreads();
    hist_mat[t * PBLOCKS + blockIdx.x] = h[t];
}

// scan_a: block-local exclusive scan of the 256K-entry matrix (1024/block)
__global__ __launch_bounds__(1024) void scan_a(const int* __restrict__ in,
                                               int* __restrict__ out,
                                               int* __restrict__ bsum) {
    __shared__ int sm[1024];
    int t = threadIdx.x, i = blockIdx.x * 1024 + t;
    int v = in[i];
    sm[t] = v;
    __syncthreads();
    for (int off = 1; off < 1024; off <<= 1) {
        int u = (t >= off) ? sm[t - off] : 0;
        __syncthreads();
        sm[t] += u;
        __syncthreads();
    }
    out[i] = sm[t] - v;
    if (t == 1023) bsum[blockIdx.x] = sm[t];
}

// scan_b: one block, exclusive scan of the 256 block sums (LDS)
__global__ __launch_bounds__(256) void scan_b(int* __restrict__ bsum) {
    __shared__ int sm[256];
    int t = threadIdx.x;
    int v = bsum[t];
    sm[t] = v;
    __syncthreads();
    for (int off = 1; off < 256; off <<= 1) {
        int u = (t >= off) ? sm[t - off] : 0;
        __syncthreads();
        sm[t] += u;
        __syncthreads();
    }
    bsum[t] = sm[t] - v;
}

__global__ __launch_bounds__(1024) void scan_c(int* __restrict__ arr,
                                               const int* __restrict__ bsum) {
    int i = blockIdx.x * 1024 + threadIdx.x;
    arr[i] += bsum[blockIdx.x];
}

__global__ __launch_bounds__(256) void partition_kernel(const int* __restrict__ ei,
                                                        const int* __restrict__ cursor_mat,
                                                        unsigned int* __restrict__ edge_part) {
    __shared__ int h[NBUCK];
    __shared__ int start[NBUCK];
    __shared__ int cur[NBUCK];
    __shared__ int gcur[NBUCK];
    __shared__ unsigned int stage[EPB];
    int t = threadIdx.x;
    h[t] = 0;
    gcur[t] = cursor_mat[t * PBLOCKS + blockIdx.x];
    __syncthreads();
    unsigned int ent[EPB / 256];
    int base = blockIdx.x * EPB;
    #pragma unroll
    for (int i = 0; i < EPB / 256; ++i) {
        int e = base + i * 256 + t;
        int s = ei[e], d = ei[N_EDGES + e];
        ent[i] = ((unsigned int)s << 16) | (unsigned int)d;   // src,dst both < 2^16
        atomicAdd(&h[d >> 8], 1);
    }
    __syncthreads();
    int v = h[t];
    start[t] = v;
    __syncthreads();
    for (int off = 1; off < 256; off <<= 1) {
        int u = (t >= off) ? start[t - off] : 0;
        __syncthreads();
        start[t] += u;
        __syncthreads();
    }
    int excl = start[t] - v;
    start[t] = excl;
    cur[t] = excl;
    __syncthreads();
    #pragma unroll
    for (int i = 0; i < EPB / 256; ++i) {
        int b = (int)((ent[i] & 0xffffu) >> 8);
        int slot = atomicAdd(&cur[b], 1);
        stage[slot] = ent[i];
    }
    __syncthreads();
    int s0 = t * (EPB / 256);
    #pragma unroll
    for (int i = 0; i < EPB / 256; ++i) {
        unsigned int p = stage[s0 + i];
        int b = (int)((p & 0xffffu) >> 8);
        edge_part[gcur[b] + (s0 + i - start[b])] = p;
    }
}

// finalize: 1024 threads/block (16 waves/CU), csr_src as ushort
__global__ __launch_bounds__(1024) void finalize_kernel(const unsigned int* __restrict__ edge_part,
                                                        const int* __restrict__ cursor_mat,
                                                        int* __restrict__ row_ptr,
                                                        unsigned short* __restrict__ csr16) {
    __shared__ int h[256];
    __shared__ int sc[256];
    __shared__ int cur[256];
    __shared__ unsigned short stage[K4CAP];
    int t = threadIdx.x;
    int b = blockIdx.x;
    if (b == NBUCK - 1 && t == 0) row_ptr[N_NODES] = N_EDGES;
    int cs = cursor_mat[b * PBLOCKS];
    int ce = (b == NBUCK - 1) ? N_EDGES : cursor_mat[(b + 1) * PBLOCKS];
    int cnt = ce - cs;
    if (t < 256) h[t] = 0;
    __syncthreads();
    for (int i = t; i < cnt; i += 1024)
        atomicAdd(&h[edge_part[cs + i] & 0xffu], 1);
    __syncthreads();
    int v = 0;
    if (t < 256) { v = h[t]; sc[t] = v; }
    __syncthreads();
    for (int off = 1; off < 256; off <<= 1) {
        int u = (t < 256 && t >= off) ? sc[t - off] : 0;
        __syncthreads();
        if (t < 256) sc[t] += u;
        __syncthreads();
    }
    if (t < 256) {
        int excl = sc[t] - v;
        row_ptr[b * 256 + t] = cs + excl;
        cur[t] = excl;
    }
    __syncthreads();
    if (cnt <= K4CAP) {
        for (int i = t; i < cnt; i += 1024) {
            unsigned int p = edge_part[cs + i];
            int slot = atomicAdd(&cur[p & 0xffu], 1);
            stage[slot] = (unsigned short)(p >> 16);
        }
        __syncthreads();
        for (int i = t; i < cnt; i += 1024)
            csr16[cs + i] = stage[i];
    } else {
        for (int i = t; i < cnt; i += 1024) {
            unsigned int p = edge_part[cs + i];
            int slot = atomicAdd(&cur[p & 0xffu], 1);
            csr16[cs + slot] = (unsigned short)(p >> 16);
        }
    }
}

// ---------------- GEMM via MFMA 16x16x32 bf16 (fp32 accum, fp16 out) ----------------
// layer 1: fp32 X input (convert to bf16 A-frags in-register)

__global__ __launch_bounds__(256) void gemm1_mfma(const float* __restrict__ X,
                                                  const float* __restrict__ W,
                                                  unsigned short* __restrict__ H) {
    constexpr int OUTC = 128;
    constexpr int NT = OUTC / 16;
    extern __shared__ unsigned short Wl[];
    int t = threadIdx.x;
    for (int idx = t; idx < OUTC * 128; idx += 256) {
        int j = idx & 7;
        int ln = (idx >> 3) & 63;
        int fc = idx >> 9;
        int kc = fc & 3, ct = fc >> 2;
        int k = kc * 32 + (ln >> 4) * 8 + j;
        int n = ct * 16 + (ln & 15);
        Wl[idx] = (unsigned short)f2bf(W[k * OUTC + n]);
    }
    __syncthreads();
    int wave = t >> 6, lane = t & 63;
    int m = lane & 15, quad = lane >> 4;
    int node_base = blockIdx.x * 64 + wave * 16;
    const float* xrow = X + (size_t)(node_base + m) * 128 + quad * 8;
    bf16x8 a[4];
    #pragma unroll
    for (int kc = 0; kc < 4; ++kc) {
        float4 u = *(const float4*)(xrow + kc * 32);
        float4 v = *(const float4*)(xrow + kc * 32 + 4);
        bf16x8 af;
        af[0] = (short)f2bf(u.x); af[1] = (short)f2bf(u.y);
        af[2] = (short)f2bf(u.z); af[3] = (short)f2bf(u.w);
        af[4] = (short)f2bf(v.x); af[5] = (short)f2bf(v.y);
        af[6] = (short)f2bf(v.z); af[7] = (short)f2bf(v.w);
        a[kc] = af;
    }
    #pragma unroll
    for (int ct = 0; ct < NT; ++ct) {
        f32x4 acc = {0.f, 0.f, 0.f, 0.f};
        #pragma unroll
        for (int kc = 0; kc < 4; ++kc) {
            bf16x8 bfr = *(const bf16x8*)(Wl + ((ct * 4 + kc) * 64 + lane) * 8);
            acc = __builtin_amdgcn_mfma_f32_16x16x32_bf16(a[kc], bfr, acc, 0, 0, 0);
        }
        #pragma unroll
        for (int r = 0; r < 4; ++r) {
            int row = quad * 4 + r;
            H[(size_t)(node_base + row) * OUTC + ct * 16 + m] = f2h(acc[r]);
        }
    }
}

// layer 2: bf16 X input (direct A-frag vector loads)

__global__ __launch_bounds__(256) void gemm2_mfma(const unsigned short* __restrict__ X,
                                                  const float* __restrict__ W,
                                                  unsigned short* __restrict__ H) {
    constexpr int OUTC = 64;
    constexpr int NT = OUTC / 16;
    extern __shared__ unsigned short Wl[];
    int t = threadIdx.x;
    for (int idx = t; idx < OUTC * 128; idx += 256) {
        int j = idx & 7;
        int ln = (idx >> 3) & 63;
        int fc = idx >> 9;
        int kc = fc & 3, ct = fc >> 2;
        int k = kc * 32 + (ln >> 4) * 8 + j;
        int n = ct * 16 + (ln & 15);
        Wl[idx] = (unsigned short)f2bf(W[k * OUTC + n]);
    }
    __syncthreads();
    int wave = t >> 6, lane = t & 63;
    int m = lane & 15, quad = lane >> 4;
    int node_base = blockIdx.x * 64 + wave * 16;
    const unsigned short* xrow = X + (size_t)(node_base + m) * 128 + quad * 8;
    bf16x8 a[4];
    #pragma unroll
    for (int kc = 0; kc < 4; ++kc) a[kc] = *(const bf16x8*)(xrow + kc * 32);
    #pragma unroll
    for (int ct = 0; ct < NT; ++ct) {
        f32x4 acc = {0.f, 0.f, 0.f, 0.f};
        #pragma unroll
        for (int kc = 0; kc < 4; ++kc) {
            bf16x8 bfr = *(const bf16x8*)(Wl + ((ct * 4 + kc) * 64 + lane) * 8);
            acc = __builtin_amdgcn_mfma_f32_16x16x32_bf16(a[kc], bfr, acc, 0, 0, 0);
        }
        #pragma unroll
        for (int r = 0; r < 4; ++r) {
            int row = quad * 4 + r;
            H[(size_t)(node_base + row) * OUTC + ct * 16 + m] = f2h(acc[r]);
        }
    }
}

// ---------------- attention logits (fp16 h) ----------------

__global__ __launch_bounds__(256) void att1_kernel(const unsigned int* __restrict__ h1u,
                                                   const float* __restrict__ as_w,
                                                   const float* __restrict__ ad_w,
                                                   float* __restrict__ a_src,
                                                   float* __restrict__ a_dst) {
    int wave = (blockIdx.x * 256 + threadIdx.x) >> 6;
    int lane = threadIdx.x & 63;
    __half2 p = u2h2(h1u[wave * 64 + lane]);
    float h0 = __low2float(p), h1v = __high2float(p);
    float2 sw = *(const float2*)(as_w + lane * 2);
    float2 dw = *(const float2*)(ad_w + lane * 2);
    float ps = h0 * sw.x + h1v * sw.y;
    float pd = h0 * dw.x + h1v * dw.y;
    #pragma unroll
    for (int m = 1; m < 16; m <<= 1) {
        ps += __shfl_xor(ps, m);
        pd += __shfl_xor(pd, m);
    }
    if ((lane & 15) == 0) {
        a_src[wave * 4 + (lane >> 4)] = ps;
        a_dst[wave * 4 + (lane >> 4)] = pd;
    }
}

__global__ __launch_bounds__(256) void att2_kernel(const __half* __restrict__ h2h,
                                                   const float* __restrict__ as_w,
                                                   const float* __restrict__ ad_w,
                                                   float* __restrict__ a_src,
                                                   float* __restrict__ a_dst) {
    int wave = (blockIdx.x * 256 + threadIdx.x) >> 6;
    int lane = threadIdx.x & 63;
    float v = __half2float(h2h[wave * 64 + lane]);
    float ps = v * as_w[lane];
    float pd = v * ad_w[lane];
    #pragma unroll
    for (int m = 1; m < 64; m <<= 1) {
        ps += __shfl_xor(ps, m);
        pd += __shfl_xor(pd, m);
    }
    if (lane == 0) {
        a_src[wave] = ps;
        a_dst[wave] = pd;
    }
}

// ---------------- edge aggregation: TWO nodes per wave (R13 structure, ushort csr) ----

__global__ __launch_bounds__(256) void agg1_kernel(const int* __restrict__ row_ptr,
                                                   const unsigned short* __restrict__ csr16,
                                                   const unsigned int* __restrict__ h1u,
                                                   const float* __restrict__ a_src,
                                                   const float* __restrict__ a_dst,
                                                   const float* __restrict__ b1,
                                                   unsigned short* __restrict__ x2) {
    int wave = (blockIdx.x * 256 + threadIdx.x) >> 6;
    int lane = threadIdx.x & 63;
    int half = lane >> 5;
    int ln = lane & 31;
    int n = wave * 2 + half;
    int j8 = ln & 7;               // batch edge slot
    int whead = ln >> 3;           // head for w-compute
    int sub = ln >> 4;             // row-slot within half (0/1)
    int col = ln & 15;             // channel group: ch col*8..+7
    int hd_c = col >> 2;           // head of this lane's channels
    int rbase = half * 32 + hd_c * 8 + sub;   // pack-lane base (+ g*2)
    float adw = a_dst[n * 4 + whead];
    int e = row_ptr[n], end = row_ptr[n + 1];
    __half2 acc0 = u2h2(0u), acc1 = u2h2(0u), acc2 = u2h2(0u), acc3 = u2h2(0u);
    float denom = 0.f;
    while (e < end) {
        int mb = end - e;
        if (mb > 8) mb = 8;
        int s_l = (int)csr16[e + (j8 < mb ? j8 : 0)];
        float l = a_src[s_l * 4 + whead] + adw;
        float wv = (j8 < mb) ? lrelu_exp_s(l) : 0.f;
        denom += wv;
        unsigned int pack = ((unsigned int)f2h(wv) << 16) | (unsigned int)s_l;
        #pragma unroll
        for (int g = 0; g < 4; ++g) {
            unsigned int pk = __shfl(pack, rbase + g * 2);
            unsigned int wu = pk >> 16;
            __half2 w2 = u2h2(wu | (wu << 16));
            unsigned int s = pk & 0xffffu;
            uint4 hv = *(const uint4*)(h1u + s * 64 + col * 4);
            acc0 = __hfma2(w2, u2h2(hv.x), acc0);
            acc1 = __hfma2(w2, u2h2(hv.y), acc1);
            acc2 = __hfma2(w2, u2h2(hv.z), acc2);
            acc3 = __hfma2(w2, u2h2(hv.w), acc3);
        }
        e += 8;
    }
    acc0 = __hadd2(acc0, u2h2(__shfl_xor(h22u(acc0), 16)));
    acc1 = __hadd2(acc1, u2h2(__shfl_xor(h22u(acc1), 16)));
    acc2 = __hadd2(acc2, u2h2(__shfl_xor(h22u(acc2), 16)));
    acc3 = __hadd2(acc3, u2h2(__shfl_xor(h22u(acc3), 16)));
    #pragma unroll
    for (int m = 1; m < 8; m <<= 1) denom += __shfl_xor(denom, m);
    float dfin = __shfl(denom, half * 32 + hd_c * 8);
    if (sub == 0) {
        float inv = 1.f / (dfin + EPS_);
        int c0 = col * 8;
        float v[8];
        v[0] = __low2float(acc0); v[1] = __high2float(acc0);
        v[2] = __low2float(acc1); v[3] = __high2float(acc1);
        v[4] = __low2float(acc2); v[5] = __high2float(acc2);
        v[6] = __low2float(acc3); v[7] = __high2float(acc3);
        unsigned int o[4];
        #pragma unroll
        for (int i = 0; i < 4; ++i) {
            float u0 = v[2 * i] * inv + b1[c0 + 2 * i];
            float u1 = v[2 * i + 1] * inv + b1[c0 + 2 * i + 1];
            u0 = 1.f / (1.f + __expf(-u0));
            u1 = 1.f / (1.f + __expf(-u1));
            o[i] = (unsigned int)f2bf(u0) | ((unsigned int)f2bf(u1) << 16);
        }
        *(uint4*)(x2 + (size_t)n * 128 + c0) = make_uint4(o[0], o[1], o[2], o[3]);
    }
}

__global__ __launch_bounds__(256) void agg2_kernel(const int* __restrict__ row_ptr,
                                                   const unsigned short* __restrict__ csr16,
                                                   const unsigned int* __restrict__ h2u,
                                                   const float* __restrict__ a_src,
                                                   const float* __restrict__ a_dst,
                                                   const float* __restrict__ b2,
                                                   float* __restrict__ out) {
    int wave = (blockIdx.x * 256 + threadIdx.x) >> 6;
    int lane = threadIdx.x & 63;
    int half = lane >> 5;
    int ln = lane & 31;
    int n = wave * 2 + half;
    int j8 = ln & 7;
    int sub = (ln >> 3) & 3;       // row-slot (4 per half)
    int col = ln & 7;              // channel group: ch col*8..+7
    int rbase = half * 32 + sub;   // pack lane (+ g*4)
    float ad = a_dst[n];
    int e = row_ptr[n], end = row_ptr[n + 1];
    __half2 acc0 = u2h2(0u), acc1 = u2h2(0u), acc2 = u2h2(0u), acc3 = u2h2(0u);
    float denom = 0.f;
    while (e < end) {
        int mb = end - e;
        if (mb > 8) mb = 8;
        int s_l = (int)csr16[e + (j8 < mb ? j8 : 0)];
        float l = a_src[s_l] + ad;
        float wv = (j8 < mb) ? lrelu_exp_s(l) : 0.f;
        denom += wv;
        unsigned int pack = ((unsigned int)f2h(wv) << 16) | (unsigned int)s_l;
        #pragma unroll
        for (int g = 0; g < 2; ++g) {
            unsigned int pk = __shfl(pack, rbase + g * 4);
            unsigned int wu = pk >> 16;
            __half2 w2 = u2h2(wu | (wu << 16));
            unsigned int s = pk & 0xffffu;
            uint4 hv = *(const uint4*)(h2u + s * 32 + col * 4);
            acc0 = __hfma2(w2, u2h2(hv.x), acc0);
            acc1 = __hfma2(w2, u2h2(hv.y), acc1);
            acc2 = __hfma2(w2, u2h2(hv.z), acc2);
            acc3 = __hfma2(w2, u2h2(hv.w), acc3);
        }
        e += 8;
    }
    #pragma unroll
    for (int m = 8; m < 32; m <<= 1) {
        acc0 = __hadd2(acc0, u2h2(__shfl_xor(h22u(acc0), m)));
        acc1 = __hadd2(acc1, u2h2(__shfl_xor(h22u(acc1), m)));
        acc2 = __hadd2(acc2, u2h2(__shfl_xor(h22u(acc2), m)));
        acc3 = __hadd2(acc3, u2h2(__shfl_xor(h22u(acc3), m)));
    }
    #pragma unroll
    for (int m = 1; m < 8; m <<= 1) denom += __shfl_xor(denom, m);
    if (sub == 0) {
        float inv = 1.f / (denom + EPS_);
        int c0 = col * 8;
        float v[8];
        v[0] = __low2float(acc0); v[1] = __high2float(acc0);
        v[2] = __low2float(acc1); v[3] = __high2float(acc1);
        v[4] = __low2float(acc2); v[5] = __high2float(acc2);
        v[6] = __low2float(acc3); v[7] = __high2float(acc3);
        float o[8];
        #pragma unroll
        for (int i = 0; i < 8; ++i) {
            float u = v[i] * inv + b2[c0 + i];
            o[i] = 1.f / (1.f + __expf(-u));
        }
        float4* dst = (float4*)(out + (size_t)n * 64 + c0);
        dst[0] = make_float4(o[0], o[1], o[2], o[3]);
        dst[1] = make_float4(o[4], o[5], o[6], o[7]);
    }
}

// ---------------- launch ----------------

extern "C" void kernel_launch(void* const* d_in, const int* in_sizes, int n_in,
                              void* d_out, int out_size, void* d_ws, size_t ws_size,
                              hipStream_t stream) {
    (void)in_sizes; (void)n_in; (void)out_size; (void)ws_size;
    const float* x   = (const float*)d_in[0];
    const int*   ei  = (const int*)d_in[1];
    const float* W1  = (const float*)d_in[2];
    const float* as1 = (const float*)d_in[3];
    const float* ad1 = (const float*)d_in[4];
    const float* b1  = (const float*)d_in[5];
    const float* W2  = (const float*)d_in[6];
    const float* as2 = (const float*)d_in[7];
    const float* ad2 = (const float*)d_in[8];
    const float* b2  = (const float*)d_in[9];
    float* out = (float*)d_out;

    char* p = (char*)d_ws;
    auto alloc = [&](size_t bytes) -> void* {
        void* r = (void*)p;
        p += (bytes + 255) & ~(size_t)255;
        return r;
    };
    int* hist_mat   = (int*)alloc((size_t)NBUCK * PBLOCKS * 4);   // 1 MB
    int* cursor_mat = (int*)alloc((size_t)NBUCK * PBLOCKS * 4);   // 1 MB
    int* bsum       = (int*)alloc(256 * 4);
    unsigned int* edge_part = (unsigned int*)alloc((size_t)N_EDGES * 4);
    int* row_ptr    = (int*)alloc((size_t)(N_NODES + 1) * 4);
    unsigned short* csr16 = (unsigned short*)alloc((size_t)N_EDGES * 2);
    unsigned short* h1 = (unsigned short*)alloc((size_t)N_NODES * 128 * 2);  // fp16
    float* a_src1   = (float*)alloc((size_t)N_NODES * 4 * 4);
    float* a_dst1   = (float*)alloc((size_t)N_NODES * 4 * 4);
    unsigned short* x2 = (unsigned short*)alloc((size_t)N_NODES * 128 * 2);  // bf16
    unsigned short* h2 = (unsigned short*)alloc((size_t)N_NODES * 64 * 2);   // fp16
    float* a_src2   = (float*)alloc((size_t)N_NODES * 4);
    float* a_dst2   = (float*)alloc((size_t)N_NODES * 4);

    // CSR build (atomic-free radix partition; 4 blocks/CU partition, 16-wave finalize)
    coarse_hist<<<PBLOCKS, 256, 0, stream>>>(ei, hist_mat);
    scan_a<<<NBUCK * PBLOCKS / 1024, 1024, 0, stream>>>(hist_mat, cursor_mat, bsum);
    scan_b<<<1, 256, 0, stream>>>(bsum);
    scan_c<<<NBUCK * PBLOCKS / 1024, 1024, 0, stream>>>(cursor_mat, bsum);
    partition_kernel<<<PBLOCKS, 256, 0, stream>>>(ei, cursor_mat, edge_part);
    finalize_kernel<<<NBUCK, 1024, 0, stream>>>(edge_part, cursor_mat, row_ptr, csr16);

    // layer 1
    gemm1_mfma<<<N_NODES / 64, 256, 128 * 128 * 2, stream>>>(x, W1, h1);
    att1_kernel<<<N_NODES / 4, 256, 0, stream>>>((const unsigned int*)h1, as1, ad1, a_src1, a_dst1);
    agg1_kernel<<<N_NODES / 8, 256, 0, stream>>>(row_ptr, csr16, (const unsigned int*)h1,
                                                 a_src1, a_dst1, b1, x2);

    // layer 2
    gemm2_mfma<<<N_NODES / 64, 256, 128 * 64 * 2, stream>>>(x2, W2, h2);
    att2_kernel<<<N_NODES / 4, 256, 0, stream>>>((const __half*)h2, as2, ad2, a_src2, a_dst2);
    agg2_kernel<<<N_NODES / 8, 256, 0, stream>>>(row_ptr, csr16, (const unsigned int*)h2,
                                                 a_src2, a_dst2, b2, out);
}